// Round 19
// baseline (73.594 us; speedup 1.0000x reference)
//
#include <hip/hip_runtime.h>
#include <stdint.h>

typedef unsigned short u16;
typedef unsigned int   u32;

#define NB 4
#define N1 8192
#define N2 2048
#define C1 128
#define C2 256
#define KK1 384          // C2 + C1
#define FF 256
#define TM 64
#define NCH 16
#define PTSA 768         // unbounded round
#define SUBA (PTSA / NCH)   // 48 pts/thread
#define PTSB 1280        // bounded round
#define SUBB (PTSB / NCH)   // 80 pts/thread
#define NPRE 8           // round-B pairs precomputed under merge barriers
#define TILES_PER_B (N1 / TM)   // 128
#define APAD 400         // u16; conflict-benign for b128 (measured)
#define HPAD 272
#define NKT1 (KK1 / 32)  // 12
#define NKT2 (FF / 32)   // 8
#define RECC 248         // out-row col where knn rec lives (6 floats)

typedef short short8 __attribute__((ext_vector_type(8)));
typedef float floatx4 __attribute__((ext_vector_type(4)));
typedef float f32x2  __attribute__((ext_vector_type(2)));
typedef u32   u32x4  __attribute__((ext_vector_type(4)));

union ABFrag { u32 u[4]; short8 v; u32x4 q; };

__device__ __forceinline__ u16 f2b(float f) {
    u32 x = __float_as_uint(f);
    return (u16)((x + 0x7FFFu + ((x >> 16) & 1u)) >> 16);
}
// RNE pack of 2 f32 -> 2 bf16 (lo = a, hi = b); same rounding as f2b
__device__ __forceinline__ u32 pack2(float a, float b) {
    u32 r;
    asm("v_cvt_pk_bf16_f32 %0, %1, %2" : "=v"(r) : "v"(a), "v"(b));
    return r;
}

// branchless exact top-3 insert (strict < : ties keep earlier-inserted/lower index)
#define INS3(d, ix, d0, d1, d2, i0, i1, i2)                         \
    {                                                               \
        float n0 = fminf(d, d0);                                    \
        float n1 = __builtin_amdgcn_fmed3f(d, d0, d1);              \
        float n2 = __builtin_amdgcn_fmed3f(d, d1, d2);              \
        bool c0 = d < d0, c1 = d < d1, c2 = d < d2;                 \
        int t01 = c0 ? i0 : ix;                                     \
        i0      = c0 ? ix : i0;                                     \
        int t12 = c1 ? i1 : t01;                                    \
        i1      = c1 ? t01 : i1;                                    \
        i2      = c2 ? t12 : i2;                                    \
        d0 = n0; d1 = n1; d2 = n2;                                  \
    }

// exact np-order pair distance: (s1+s2) - 2*dot, plain-rounded, packed 2-wide
#define DPAIR(f0, f1, qx, qy, qz, s1, out)                          \
    {                                                               \
        _Pragma("clang fp contract(off)")                           \
        f32x2 qx2 = {qx, qx}, qy2 = {qy, qy}, qz2 = {qz, qz};       \
        f32x2 s1v = {s1, s1};                                       \
        f32x2 nx = {f0.x, f0.y}, ny = {f0.z, f0.w};                 \
        f32x2 nz = {f1.x, f1.y}, ss = {f1.z, f1.w};                 \
        f32x2 u  = qx2 * nx;                                        \
        f32x2 v  = qy2 * ny;                                        \
        f32x2 w  = u + v;                                           \
        f32x2 z2 = qz2 * nz;                                        \
        f32x2 t  = w + z2;                                          \
        f32x2 s12 = s1v + ss;                                       \
        out = s12 + t;                                              \
    }

// ---- prep: coalesced LDS-transpose weight fragments + xq table ----
__global__ __launch_bounds__(1024) void prep_kernel(
    const float* __restrict__ w1, const float* __restrict__ w2,
    const float* __restrict__ xyz2,
    u32x4* __restrict__ w1F, u32x4* __restrict__ w2F, float* __restrict__ xq)
{
    __shared__ float lds[32][257];
    const int tid = threadIdx.x;
    const int blk = blockIdx.x;

    if (blk < NKT1 + NKT2) {
        const bool isw1 = blk < NKT1;
        const int  kt   = isw1 ? blk : blk - NKT1;
        const float* src = (isw1 ? w1 : w2) + (size_t)kt * 32 * FF;
        #pragma unroll
        for (int i = 0; i < 8; ++i) {
            int e = tid + i * 1024;             // 32*256 = 8192 elems, coalesced
            lds[e >> 8][e & 255] = src[e];
        }
        __syncthreads();
        const int nt = tid >> 6, lane = tid & 63;
        const int n  = nt * 16 + (lane & 15);
        const int k0 = (lane >> 4) * 8;
        ABFrag f;
        f.u[0] = pack2(lds[k0 + 0][n], lds[k0 + 1][n]);
        f.u[1] = pack2(lds[k0 + 2][n], lds[k0 + 3][n]);
        f.u[2] = pack2(lds[k0 + 4][n], lds[k0 + 5][n]);
        f.u[3] = pack2(lds[k0 + 6][n], lds[k0 + 7][n]);
        if (isw1) w1F[(size_t)(nt * NKT1 + kt) * 64 + lane] = f.q;
        else      w2F[(size_t)(nt * NKT2 + kt) * 64 + lane] = f.q;
        return;
    }

    int i = (blk - NKT1 - NKT2) * 1024 + tid;   // 0 .. NB*N2-1
    const float* q = xyz2 + (size_t)i * 3;
    float x = q[0], y = q[1], z = q[2];
    float s2 = __fadd_rn(__fadd_rn(__fmul_rn(x,x), __fmul_rn(y,y)), __fmul_rn(z,z));
    int p = i >> 1, e = i & 1;
    float* rec = xq + (size_t)p * 8;
    rec[0 + e] = -2.0f * x;
    rec[2 + e] = -2.0f * y;
    rec[4 + e] = -2.0f * z;
    rec[6 + e] = s2;
}

// ---- kernel A: two-round bounded 3-NN only; 512 x 1024thr = 32 waves/CU ----
// Writes per-row rec {w0,w1,w2,i0,i1,i2} to out[row][248..253] (B overwrites later).
__global__ __launch_bounds__(1024, 8) void knn_kernel(
    const float* __restrict__ xyz1, const float4* __restrict__ xq,
    float* __restrict__ out)
{
    __shared__ float s_m[TM][8];
    __shared__ float s_pd[NCH * TM * 3];
    __shared__ int   s_pi[NCH * TM * 3];
    __shared__ float s_g[TM][4][8];              // level-1 merge partials

    const int tid = threadIdx.x;
    const int b   = blockIdx.x / TILES_PER_B;
    const int t0  = (blockIdx.x % TILES_PER_B) * TM;

    const int r  = tid & 63;
    const int ch = __builtin_amdgcn_readfirstlane(tid >> 6);   // 0..15, wave-uniform

    const float* q = xyz1 + ((size_t)b * N1 + t0 + r) * 3;
    const float qx = q[0], qy = q[1], qz = q[2];
    const float s1 = __fadd_rn(__fadd_rn(__fmul_rn(qx,qx), __fmul_rn(qy,qy)), __fmul_rn(qz,qz));

    // ---------- round A: pts [SUBA*ch, +SUBA) of first PTSA, unbounded ----------
    {
        const float4* cb = xq + ((size_t)b * (N2 / 2) + ch * (SUBA / 2)) * 2;
        float bd0 = 3e38f, bd1 = 3e38f, bd2 = 3e38f;
        int   bi0 = -1, bi1 = -1, bi2 = -1;
        const int j0 = ch * SUBA;
        #pragma unroll 8
        for (int jj = 0; jj < SUBA / 2; ++jj) {
            float4 f0 = cb[2 * jj];        // (nx0,nx1,ny0,ny1)
            float4 f1 = cb[2 * jj + 1];    // (nz0,nz1,s20,s21)
            f32x2 dpair;
            DPAIR(f0, f1, qx, qy, qz, s1, dpair);
            #pragma unroll
            for (int e = 0; e < 2; ++e) {
                float d = dpair[e];
                int   j = j0 + 2 * jj + e;
                INS3(d, j, bd0, bd1, bd2, bi0, bi1, bi2);
            }
        }
        const int o = (ch * TM + r) * 3;
        s_pd[o+0] = bd0; s_pd[o+1] = bd1; s_pd[o+2] = bd2;
        s_pi[o+0] = bi0; s_pi[o+1] = bi1; s_pi[o+2] = bi2;
    }

    // precompute first NPRE round-B pair distances (hidden under merge barriers)
    const float4* cbB = xq + ((size_t)b * (N2 / 2) + (PTSA / 2) + ch * (SUBB / 2)) * 2;
    f32x2 preB[NPRE];
    #pragma unroll
    for (int jj = 0; jj < NPRE; ++jj) {
        float4 f0 = cbB[2 * jj];
        float4 f1 = cbB[2 * jj + 1];
        DPAIR(f0, f1, qx, qy, qz, s1, preB[jj]);
    }
    __syncthreads();

    // ---------- merge A level 1: 256 threads, 4 chunks each (ascending) ----------
    if (tid < 256) {
        const int row = tid & 63, grp = tid >> 6;        // grp 0..3
        float d0 = 3e38f, d1 = 3e38f, d2 = 3e38f;
        int   i0 = -1, i1 = -1, i2 = -1;
        #pragma unroll
        for (int c = 0; c < 4; ++c) {
            const int o = ((grp * 4 + c) * TM + row) * 3;
            #pragma unroll
            for (int k = 0; k < 3; ++k) {
                float d = s_pd[o + k]; int ix = s_pi[o + k];
                INS3(d, ix, d0, d1, d2, i0, i1, i2);
            }
        }
        s_g[row][grp][0] = d0; s_g[row][grp][1] = d1; s_g[row][grp][2] = d2;
        s_g[row][grp][3] = __int_as_float(i0);
        s_g[row][grp][4] = __int_as_float(i1);
        s_g[row][grp][5] = __int_as_float(i2);
    }
    __syncthreads();

    // ---------- merge A level 2: 64 threads, 4 group-partials (ascending) ----------
    if (tid < TM) {
        float d0 = 3e38f, d1 = 3e38f, d2 = 3e38f;
        int   i0 = -1, i1 = -1, i2 = -1;
        #pragma unroll
        for (int g = 0; g < 4; ++g) {
            #pragma unroll
            for (int k = 0; k < 3; ++k) {
                float d = s_g[tid][g][k]; int ix = __float_as_int(s_g[tid][g][3 + k]);
                INS3(d, ix, d0, d1, d2, i0, i1, i2);
            }
        }
        s_m[tid][0] = d0; s_m[tid][1] = d1; s_m[tid][2] = d2;
        s_m[tid][4] = __int_as_float(i0);
        s_m[tid][5] = __int_as_float(i1);
        s_m[tid][6] = __int_as_float(i2);
    }
    __syncthreads();

    // ---------- round B: pts [PTSA + SUBB*ch, +SUBB), bound-skip ----------
    {
        const float bound = s_m[r][2];   // exact d2 of first PTSA; later pts with
                                         // d >= bound cannot enter global top3 (ties lose)
        float bd0 = bound, bd1 = bound, bd2 = bound;
        int   bi0 = -1, bi1 = -1, bi2 = -1;
        const int j0 = PTSA + ch * SUBB;
        #pragma unroll
        for (int jj = 0; jj < NPRE; ++jj) {
            f32x2 dpair = preB[jj];
            if (__any((dpair.x < bd2) || (dpair.y < bd2))) {
                #pragma unroll
                for (int e = 0; e < 2; ++e) {
                    float d = dpair[e];
                    int   j = j0 + 2 * jj + e;
                    INS3(d, j, bd0, bd1, bd2, bi0, bi1, bi2);
                }
            }
        }
        #pragma unroll 4
        for (int jj = NPRE; jj < SUBB / 2; ++jj) {
            float4 f0 = cbB[2 * jj];
            float4 f1 = cbB[2 * jj + 1];
            f32x2 dpair;
            DPAIR(f0, f1, qx, qy, qz, s1, dpair);
            if (__any((dpair.x < bd2) || (dpair.y < bd2))) {
                #pragma unroll
                for (int e = 0; e < 2; ++e) {
                    float d = dpair[e];
                    int   j = j0 + 2 * jj + e;
                    INS3(d, j, bd0, bd1, bd2, bi0, bi1, bi2);
                }
            }
        }
        const int o = (ch * TM + r) * 3;
        s_pd[o+0] = bd0; s_pd[o+1] = bd1; s_pd[o+2] = bd2;
        s_pi[o+0] = bi0; s_pi[o+1] = bi1; s_pi[o+2] = bi2;
    }
    __syncthreads();

    // ---------- merge B level 1: 256 threads, 4 chunks each ----------
    if (tid < 256) {
        const int row = tid & 63, grp = tid >> 6;
        float d0 = 3e38f, d1 = 3e38f, d2 = 3e38f;
        int   i0 = -1, i1 = -1, i2 = -1;
        #pragma unroll
        for (int c = 0; c < 4; ++c) {
            const int o = ((grp * 4 + c) * TM + row) * 3;
            #pragma unroll
            for (int k = 0; k < 3; ++k) {
                float d = s_pd[o + k]; int ix = s_pi[o + k];
                INS3(d, ix, d0, d1, d2, i0, i1, i2);
            }
        }
        s_g[row][grp][0] = d0; s_g[row][grp][1] = d1; s_g[row][grp][2] = d2;
        s_g[row][grp][3] = __int_as_float(i0);
        s_g[row][grp][4] = __int_as_float(i1);
        s_g[row][grp][5] = __int_as_float(i2);
    }
    __syncthreads();

    // ---------- merge B level 2: init from A-top3; weights; store rec ----------
    if (tid < TM) {
        float d0 = s_m[tid][0], d1 = s_m[tid][1], d2 = s_m[tid][2];
        int   i0 = __float_as_int(s_m[tid][4]);
        int   i1 = __float_as_int(s_m[tid][5]);
        int   i2 = __float_as_int(s_m[tid][6]);
        #pragma unroll
        for (int g = 0; g < 4; ++g) {
            #pragma unroll
            for (int k = 0; k < 3; ++k) {
                // fake (bound,-1) entries have d >= current d2 -> rejected by strict <
                float d = s_g[tid][g][k]; int ix = __float_as_int(s_g[tid][g][3 + k]);
                INS3(d, ix, d0, d1, d2, i0, i1, i2);
            }
        }
        d0 = fmaxf(d0, 1e-10f); d1 = fmaxf(d1, 1e-10f); d2 = fmaxf(d2, 1e-10f);
        float v0 = 1.0f / d0, v1 = 1.0f / d1, v2 = 1.0f / d2;
        float s  = 1.0f / (v0 + v1 + v2);
        float* rp = out + ((size_t)(b * N1 + t0 + tid) * FF + RECC);
        *(float2*)(rp)     = make_float2(v0 * s, v1 * s);
        *(float2*)(rp + 2) = make_float2(v2 * s, __int_as_float(i0));
        *(float2*)(rp + 4) = make_float2(__int_as_float(i1), __int_as_float(i2));
    }
}

// ---- kernel B: interp + concat + mlp(2x); 512thr, 3 blocks/CU ----
__global__ __launch_bounds__(512, 6) void gemm_kernel(
    const float* __restrict__ p1, const float* __restrict__ p2,
    const u32x4* __restrict__ w1F, const u32x4* __restrict__ w2F,
    float* __restrict__ out)
{
    __shared__ int   s_idx[TM][3];
    __shared__ float s_wt[TM][3];
    __shared__ __align__(16) char s_buf[TM * APAD * 2];   // A tile; H overlays

    const int tid = threadIdx.x;
    const int b   = blockIdx.x / TILES_PER_B;
    const int t0  = (blockIdx.x % TILES_PER_B) * TM;
    u16* A = (u16*)s_buf;

    // ---------- phase 0: knn recs + p1 -> A cols 256..383 ----------
    if (tid < TM) {
        const float* rp = out + ((size_t)(b * N1 + t0 + tid) * FF + RECC);
        float2 a0 = *(const float2*)(rp);
        float2 a1 = *(const float2*)(rp + 2);
        float2 a2 = *(const float2*)(rp + 4);
        s_wt[tid][0] = a0.x; s_wt[tid][1] = a0.y; s_wt[tid][2] = a1.x;
        s_idx[tid][0] = __float_as_int(a1.y);
        s_idx[tid][1] = __float_as_int(a2.x);
        s_idx[tid][2] = __float_as_int(a2.y);
    }
    {
        const int c4 = (tid & 31) * 4, r16 = tid >> 5;   // 0..15
        #pragma unroll
        for (int rv = 0; rv < 4; ++rv) {
            int rr = r16 + rv * 16;
            float4 v = *(const float4*)(p1 + ((size_t)b * N1 + t0 + rr) * C1 + c4);
            u32* w = (u32*)(A + rr * APAD + 256 + c4);
            w[0] = pack2(v.x, v.y);
            w[1] = pack2(v.z, v.w);
        }
    }
    __syncthreads();

    // ---------- phase 1: interp -> A cols 0..255 (wave-uniform row, 2-deep pipe) ----------
    {
        const float* pb = p2 + (size_t)b * N2 * C2;
        const int col4 = (tid & 63) * 4;
        const int wvr  = tid >> 6;                       // 0..7
        float4 a0[2], a1[2], a2[2];
        {
            int rr = wvr;
            a0[0] = *(const float4*)(pb + (size_t)s_idx[rr][0] * C2 + col4);
            a1[0] = *(const float4*)(pb + (size_t)s_idx[rr][1] * C2 + col4);
            a2[0] = *(const float4*)(pb + (size_t)s_idx[rr][2] * C2 + col4);
        }
        #pragma unroll
        for (int m = 0; m < 8; ++m) {
            int cur = m & 1, nxt = cur ^ 1;
            if (m < 7) {
                int rn = wvr + (m + 1) * 8;
                a0[nxt] = *(const float4*)(pb + (size_t)s_idx[rn][0] * C2 + col4);
                a1[nxt] = *(const float4*)(pb + (size_t)s_idx[rn][1] * C2 + col4);
                a2[nxt] = *(const float4*)(pb + (size_t)s_idx[rn][2] * C2 + col4);
            }
            int rr = wvr + m * 8;
            float w0 = s_wt[rr][0], w1v = s_wt[rr][1], w2v = s_wt[rr][2];
            float e0 = w0 * a0[cur].x + w1v * a1[cur].x + w2v * a2[cur].x;
            float e1 = w0 * a0[cur].y + w1v * a1[cur].y + w2v * a2[cur].y;
            float e2 = w0 * a0[cur].z + w1v * a1[cur].z + w2v * a2[cur].z;
            float e3 = w0 * a0[cur].w + w1v * a1[cur].w + w2v * a2[cur].w;
            u32* w = (u32*)(A + rr * APAD + col4);
            w[0] = pack2(e0, e1);
            w[1] = pack2(e2, e3);
        }
    }
    __syncthreads();

    // ---------- lane/wave constants + C/D map probe ----------
    const int lane = tid & 63;
    const int wv   = tid >> 6;          // 0..7, wave -> 32-col slice (2 nt tiles)
    const int lr   = lane & 15;
    const int lg   = lane >> 4;         // 0..3
    const int kb8  = lg * 8;
    const int nt0  = wv * 2;

    int id1[4], id2[4];
    {
        u16 rbf = f2b((float)lr);
        u16 c32 = f2b(1.0f / 32.0f);
        ABFrag pa, pc;
        u32 ra = (u32)rbf | ((u32)rbf << 16);
        u32 rc = (u32)c32 | ((u32)c32 << 16);
        pa.u[0] = pa.u[1] = pa.u[2] = pa.u[3] = ra;
        pc.u[0] = pc.u[1] = pc.u[2] = pc.u[3] = rc;
        floatx4 z = {0.f, 0.f, 0.f, 0.f};
        floatx4 D1 = __builtin_amdgcn_mfma_f32_16x16x32_bf16(pa.v, pc.v, z, 0, 0, 0); // row
        floatx4 D2 = __builtin_amdgcn_mfma_f32_16x16x32_bf16(pc.v, pa.v, z, 0, 0, 0); // col
        #pragma unroll
        for (int g = 0; g < 4; ++g) { id1[g] = (int)(D1[g] + 0.5f); id2[g] = (int)(D2[g] + 0.5f); }
    }

    // ---------- GEMM1 (K=384): 4 row-tiles x 2 col-tiles, 1-deep prefetch ----------
    floatx4 acc[4][2];
    #pragma unroll
    for (int i = 0; i < 4; ++i)
        #pragma unroll
        for (int j = 0; j < 2; ++j) acc[i][j] = floatx4{0.f, 0.f, 0.f, 0.f};
    {
        ABFrag bfc[2];
        bfc[0].q = w1F[(size_t)((nt0 + 0) * NKT1) * 64 + lane];
        bfc[1].q = w1F[(size_t)((nt0 + 1) * NKT1) * 64 + lane];
        #pragma unroll 2
        for (int kk = 0; kk < NKT1; ++kk) {
            int kn = (kk + 1 < NKT1) ? kk + 1 : kk;
            ABFrag bfn[2];
            bfn[0].q = w1F[(size_t)((nt0 + 0) * NKT1 + kn) * 64 + lane];
            bfn[1].q = w1F[(size_t)((nt0 + 1) * NKT1 + kn) * 64 + lane];
            ABFrag a[4];
            #pragma unroll
            for (int rt = 0; rt < 4; ++rt)
                a[rt].q = *(const u32x4*)(A + (rt * 16 + lr) * APAD + kk * 32 + kb8);
            #pragma unroll
            for (int rt = 0; rt < 4; ++rt)
                #pragma unroll
                for (int ct = 0; ct < 2; ++ct)
                    acc[rt][ct] = __builtin_amdgcn_mfma_f32_16x16x32_bf16(a[rt].v, bfc[ct].v, acc[rt][ct], 0, 0, 0);
            bfc[0] = bfn[0]; bfc[1] = bfn[1];
        }
    }
    __syncthreads();   // all waves done reading A

    // ---------- H = relu -> bf16 LDS [TM][HPAD] ----------
    u16* H = (u16*)s_buf;
    #pragma unroll
    for (int rt = 0; rt < 4; ++rt)
        #pragma unroll
        for (int ct = 0; ct < 2; ++ct)
            #pragma unroll
            for (int g = 0; g < 4; ++g) {
                int row = rt * 16 + id1[g];
                int col = wv * 32 + ct * 16 + id2[g];
                H[row * HPAD + col] = f2b(fmaxf(acc[rt][ct][g], 0.0f));
            }
    __syncthreads();

    // ---------- GEMM2 (K=256): 4x2 tiles, 1-deep prefetch ----------
    floatx4 acc2[4][2];
    #pragma unroll
    for (int i = 0; i < 4; ++i)
        #pragma unroll
        for (int j = 0; j < 2; ++j) acc2[i][j] = floatx4{0.f, 0.f, 0.f, 0.f};
    {
        ABFrag bfc[2];
        bfc[0].q = w2F[(size_t)((nt0 + 0) * NKT2) * 64 + lane];
        bfc[1].q = w2F[(size_t)((nt0 + 1) * NKT2) * 64 + lane];
        #pragma unroll 2
        for (int kk = 0; kk < NKT2; ++kk) {
            int kn = (kk + 1 < NKT2) ? kk + 1 : kk;
            ABFrag bfn[2];
            bfn[0].q = w2F[(size_t)((nt0 + 0) * NKT2 + kn) * 64 + lane];
            bfn[1].q = w2F[(size_t)((nt0 + 1) * NKT2 + kn) * 64 + lane];
            ABFrag a[4];
            #pragma unroll
            for (int rt = 0; rt < 4; ++rt)
                a[rt].q = *(const u32x4*)(H + (rt * 16 + lr) * HPAD + kk * 32 + kb8);
            #pragma unroll
            for (int rt = 0; rt < 4; ++rt)
                #pragma unroll
                for (int ct = 0; ct < 2; ++ct)
                    acc2[rt][ct] = __builtin_amdgcn_mfma_f32_16x16x32_bf16(a[rt].v, bfc[ct].v, acc2[rt][ct], 0, 0, 0);
            bfc[0] = bfn[0]; bfc[1] = bfn[1];
        }
    }

    // ---------- relu -> f32 -> global ----------
    float* ob = out + ((size_t)b * N1 + t0) * FF;
    #pragma unroll
    for (int rt = 0; rt < 4; ++rt)
        #pragma unroll
        for (int ct = 0; ct < 2; ++ct)
            #pragma unroll
            for (int g = 0; g < 4; ++g) {
                int row = rt * 16 + id1[g];
                int col = wv * 32 + ct * 16 + id2[g];
                ob[(size_t)row * FF + col] = fmaxf(acc2[rt][ct][g], 0.0f);
            }
}

extern "C" void kernel_launch(void* const* d_in, const int* in_sizes, int n_in,
                              void* d_out, int out_size, void* d_ws, size_t ws_size,
                              hipStream_t stream)
{
    (void)in_sizes; (void)n_in; (void)out_size; (void)ws_size;
    const float* xyz1 = (const float*)d_in[0];
    const float* xyz2 = (const float*)d_in[1];
    const float* p1   = (const float*)d_in[2];
    const float* p2   = (const float*)d_in[3];
    const float* w1   = (const float*)d_in[4];
    const float* w2   = (const float*)d_in[5];
    float* out = (float*)d_out;

    u32x4* w1F = (u32x4*)d_ws;                      // 196608 B
    u32x4* w2F = w1F + 16 * NKT1 * 64;              // 131072 B
    float* xqw = (float*)(w2F + 16 * NKT2 * 64);    // 131072 B

    prep_kernel<<<NKT1 + NKT2 + (NB * N2 / 1024), 1024, 0, stream>>>(
        w1, w2, xyz2, w1F, w2F, xqw);
    knn_kernel<<<NB * TILES_PER_B, 1024, 0, stream>>>(xyz1, (const float4*)xqw, out);
    gemm_kernel<<<NB * TILES_PER_B, 512, 0, stream>>>(p1, p2, w1F, w2F, out);
}

// Round 20
// 57.142 us; speedup vs baseline: 1.2879x; 1.2879x over previous
//
#include <hip/hip_runtime.h>
#include <stdint.h>

typedef unsigned short u16;
typedef unsigned int   u32;

#define NB 4
#define N1 8192
#define N2 2048
#define C1 128
#define C2 256
#define KK1 384          // C2 + C1
#define FF 256
#define TM 64
#define NTHR 1024
#define NCH 16
#define PTSA 768         // unbounded round
#define SUBA (PTSA / NCH)   // 48 pts/thread
#define PTSB 1280        // bounded round
#define SUBB (PTSB / NCH)   // 80 pts/thread
#define TILES_PER_B (N1 / TM)   // 128
#define APAD 400         // u16; conflict-benign for b128 (measured)
#define HPAD 272
#define NKT1 (KK1 / 32)  // 12
#define NKT2 (FF / 32)   // 8

typedef short short8 __attribute__((ext_vector_type(8)));
typedef float floatx4 __attribute__((ext_vector_type(4)));
typedef float f32x2  __attribute__((ext_vector_type(2)));
typedef u32   u32x4  __attribute__((ext_vector_type(4)));

union ABFrag { u32 u[4]; short8 v; u32x4 q; };

__device__ __forceinline__ u16 f2b(float f) {
    u32 x = __float_as_uint(f);
    return (u16)((x + 0x7FFFu + ((x >> 16) & 1u)) >> 16);
}
// RNE pack of 2 f32 -> 2 bf16 (lo = a, hi = b); same rounding as f2b
__device__ __forceinline__ u32 pack2(float a, float b) {
    u32 r;
    asm("v_cvt_pk_bf16_f32 %0, %1, %2" : "=v"(r) : "v"(a), "v"(b));
    return r;
}

// branchless exact top-3 insert (strict < : ties keep earlier-inserted/lower index)
#define INS3(d, ix, d0, d1, d2, i0, i1, i2)                         \
    {                                                               \
        float n0 = fminf(d, d0);                                    \
        float n1 = __builtin_amdgcn_fmed3f(d, d0, d1);              \
        float n2 = __builtin_amdgcn_fmed3f(d, d1, d2);              \
        bool c0 = d < d0, c1 = d < d1, c2 = d < d2;                 \
        int t01 = c0 ? i0 : ix;                                     \
        i0      = c0 ? ix : i0;                                     \
        int t12 = c1 ? i1 : t01;                                    \
        i1      = c1 ? t01 : i1;                                    \
        i2      = c2 ? t12 : i2;                                    \
        d0 = n0; d1 = n1; d2 = n2;                                  \
    }

// exact np-order pair distance: (s1+s2) - 2*dot, plain-rounded, packed 2-wide
#define DPAIR(f0, f1, qx, qy, qz, s1, out)                          \
    {                                                               \
        _Pragma("clang fp contract(off)")                           \
        f32x2 qx2 = {qx, qx}, qy2 = {qy, qy}, qz2 = {qz, qz};       \
        f32x2 s1v = {s1, s1};                                       \
        f32x2 nx = {f0.x, f0.y}, ny = {f0.z, f0.w};                 \
        f32x2 nz = {f1.x, f1.y}, ss = {f1.z, f1.w};                 \
        f32x2 u  = qx2 * nx;                                        \
        f32x2 v  = qy2 * ny;                                        \
        f32x2 w  = u + v;                                           \
        f32x2 z2 = qz2 * nz;                                        \
        f32x2 t  = w + z2;                                          \
        f32x2 s12 = s1v + ss;                                       \
        out = s12 + t;                                              \
    }

// ---- prep: contiguous-k weight fragments + paired (-2x,-2y,-2z,|x|^2) table ----
__global__ __launch_bounds__(256) void prep_kernel(
    const float* __restrict__ w1, const float* __restrict__ w2,
    const float* __restrict__ xyz2,
    u32x4* __restrict__ w1F, u32x4* __restrict__ w2F, float* __restrict__ xq)
{
    int i = blockIdx.x * 256 + threadIdx.x;
    if (i < 16 * NKT1 * 64) {                       // w1 fragments [nt][kt][lane]
        int nt = i / (NKT1 * 64), rem = i % (NKT1 * 64);
        int kt = rem / 64, lane = rem % 64;
        int n  = nt * 16 + (lane & 15);
        int k0 = kt * 32 + (lane >> 4) * 8;
        const float* wc = w1 + n;
        ABFrag f;
        f.u[0] = pack2(wc[(k0 + 0) * FF], wc[(k0 + 1) * FF]);
        f.u[1] = pack2(wc[(k0 + 2) * FF], wc[(k0 + 3) * FF]);
        f.u[2] = pack2(wc[(k0 + 4) * FF], wc[(k0 + 5) * FF]);
        f.u[3] = pack2(wc[(k0 + 6) * FF], wc[(k0 + 7) * FF]);
        w1F[i] = f.q;
        return;
    }
    i -= 16 * NKT1 * 64;
    if (i < 16 * NKT2 * 64) {                       // w2 fragments
        int nt = i / (NKT2 * 64), rem = i % (NKT2 * 64);
        int kt = rem / 64, lane = rem % 64;
        int n  = nt * 16 + (lane & 15);
        int k0 = kt * 32 + (lane >> 4) * 8;
        const float* wc = w2 + n;
        ABFrag f;
        f.u[0] = pack2(wc[(k0 + 0) * FF], wc[(k0 + 1) * FF]);
        f.u[1] = pack2(wc[(k0 + 2) * FF], wc[(k0 + 3) * FF]);
        f.u[2] = pack2(wc[(k0 + 4) * FF], wc[(k0 + 5) * FF]);
        f.u[3] = pack2(wc[(k0 + 6) * FF], wc[(k0 + 7) * FF]);
        w2F[i] = f.q;
        return;
    }
    i -= 16 * NKT2 * 64;
    if (i < NB * N2) {                              // xq: pair records of 8 floats
        const float* q = xyz2 + (size_t)i * 3;
        float x = q[0], y = q[1], z = q[2];
        float s2 = __fadd_rn(__fadd_rn(__fmul_rn(x,x), __fmul_rn(y,y)), __fmul_rn(z,z));
        int p = i >> 1, e = i & 1;
        float* rec = xq + (size_t)p * 8;
        rec[0 + e] = -2.0f * x;
        rec[2 + e] = -2.0f * y;
        rec[4 + e] = -2.0f * z;
        rec[6 + e] = s2;
    }
}

// ---- fused: two-round bounded 3nn + interp + concat + mlp(2x) ----
__global__ __launch_bounds__(NTHR, 8) void fp_fused_kernel(
    const float* __restrict__ xyz1, const float* __restrict__ p1,
    const float* __restrict__ p2,
    const u32x4* __restrict__ w1F,  const u32x4* __restrict__ w2F,
    const float4* __restrict__ xq,  float* __restrict__ out)
{
    __shared__ int   s_idx[TM][3];
    __shared__ float s_wt[TM][3];
    __shared__ float s_m[TM][8];                 // round-A top3: d0,d1,d2,-,i0,i1,i2,-
    __shared__ float s_pd[NCH * TM * 3];
    __shared__ int   s_pi[NCH * TM * 3];
    __shared__ __align__(16) char s_buf[TM * APAD * 2];   // A tile; H overlays
    // merge level-1 partials overlay A cols 0..255 (free until interp):
    // slot (row,grp) at byte offset row*800 + grp*32 (24B used of 32)

    const int tid = threadIdx.x;
    const int b   = blockIdx.x / TILES_PER_B;
    const int t0  = (blockIdx.x % TILES_PER_B) * TM;
    u16* A = (u16*)s_buf;

    // ---------- phase 0: ISSUE p1 loads (defer LDS write past round A) ----------
    const int c4 = (tid & 31) * 4, r32 = tid >> 5;       // 0..31
    float4 pv0 = *(const float4*)(p1 + ((size_t)b * N1 + t0 + r32) * C1 + c4);
    float4 pv1 = *(const float4*)(p1 + ((size_t)b * N1 + t0 + r32 + 32) * C1 + c4);

    const int r  = tid & 63;
    const int ch = __builtin_amdgcn_readfirstlane(tid >> 6);   // 0..15, wave-uniform

    const float* q = xyz1 + ((size_t)b * N1 + t0 + r) * 3;
    const float qx = q[0], qy = q[1], qz = q[2];
    const float s1 = __fadd_rn(__fadd_rn(__fmul_rn(qx,qx), __fmul_rn(qy,qy)), __fmul_rn(qz,qz));

    // ---------- round A: pts [SUBA*ch, +SUBA) of first PTSA, unbounded ----------
    {
        const float4* cb = xq + ((size_t)b * (N2 / 2) + ch * (SUBA / 2)) * 2;
        float bd0 = 3e38f, bd1 = 3e38f, bd2 = 3e38f;
        int   bi0 = -1, bi1 = -1, bi2 = -1;
        const int j0 = ch * SUBA;
        #pragma unroll 8
        for (int jj = 0; jj < SUBA / 2; ++jj) {
            float4 f0 = cb[2 * jj];        // (nx0,nx1,ny0,ny1)
            float4 f1 = cb[2 * jj + 1];    // (nz0,nz1,s20,s21)
            f32x2 dpair;
            DPAIR(f0, f1, qx, qy, qz, s1, dpair);
            #pragma unroll
            for (int e = 0; e < 2; ++e) {
                float d = dpair[e];
                int   j = j0 + 2 * jj + e;
                INS3(d, j, bd0, bd1, bd2, bi0, bi1, bi2);
            }
        }
        const int o = (ch * TM + r) * 3;
        s_pd[o+0] = bd0; s_pd[o+1] = bd1; s_pd[o+2] = bd2;
        s_pi[o+0] = bi0; s_pi[o+1] = bi1; s_pi[o+2] = bi2;
    }

    // p1 regs -> A cols 256..383 (loads long since landed, hidden under scan)
    {
        u32* w0 = (u32*)(A + r32 * APAD + 256 + c4);
        w0[0] = pack2(pv0.x, pv0.y);
        w0[1] = pack2(pv0.z, pv0.w);
        u32* w1p = (u32*)(A + (r32 + 32) * APAD + 256 + c4);
        w1p[0] = pack2(pv1.x, pv1.y);
        w1p[1] = pack2(pv1.z, pv1.w);
    }
    __syncthreads();

    // ---------- merge A level 1: 256 threads, 4 chunks each (ascending) ----------
    if (tid < 256) {
        const int row = tid & 63, grp = tid >> 6;        // grp 0..3
        float d0 = 3e38f, d1 = 3e38f, d2 = 3e38f;
        int   i0 = -1, i1 = -1, i2 = -1;
        #pragma unroll
        for (int c = 0; c < 4; ++c) {
            const int o = ((grp * 4 + c) * TM + row) * 3;
            #pragma unroll
            for (int k = 0; k < 3; ++k) {
                float d = s_pd[o + k]; int ix = s_pi[o + k];
                INS3(d, ix, d0, d1, d2, i0, i1, i2);
            }
        }
        float* sg = (float*)(s_buf + row * (APAD * 2) + grp * 32);
        sg[0] = d0; sg[1] = d1; sg[2] = d2;
        sg[3] = __int_as_float(i0); sg[4] = __int_as_float(i1); sg[5] = __int_as_float(i2);
    }
    __syncthreads();

    // ---------- merge A level 2: 64 threads, 4 group-partials (ascending) ----------
    if (tid < TM) {
        float d0 = 3e38f, d1 = 3e38f, d2 = 3e38f;
        int   i0 = -1, i1 = -1, i2 = -1;
        #pragma unroll
        for (int g = 0; g < 4; ++g) {
            const float* sg = (const float*)(s_buf + tid * (APAD * 2) + g * 32);
            #pragma unroll
            for (int k = 0; k < 3; ++k) {
                float d = sg[k]; int ix = __float_as_int(sg[3 + k]);
                INS3(d, ix, d0, d1, d2, i0, i1, i2);
            }
        }
        s_m[tid][0] = d0; s_m[tid][1] = d1; s_m[tid][2] = d2;
        s_m[tid][4] = __int_as_float(i0);
        s_m[tid][5] = __int_as_float(i1);
        s_m[tid][6] = __int_as_float(i2);
    }
    __syncthreads();

    // ---------- round B: pts [PTSA + SUBB*ch, +SUBB), bound-skip ----------
    {
        const float bound = s_m[r][2];   // exact d2 of first PTSA; later pts with
                                         // d >= bound cannot enter global top3 (ties lose)
        const float4* cb = xq + ((size_t)b * (N2 / 2) + (PTSA / 2) + ch * (SUBB / 2)) * 2;
        float bd0 = bound, bd1 = bound, bd2 = bound;
        int   bi0 = -1, bi1 = -1, bi2 = -1;
        const int j0 = PTSA + ch * SUBB;
        #pragma unroll 4
        for (int jj = 0; jj < SUBB / 2; ++jj) {
            float4 f0 = cb[2 * jj];
            float4 f1 = cb[2 * jj + 1];
            f32x2 dpair;
            DPAIR(f0, f1, qx, qy, qz, s1, dpair);
            if (__any((dpair.x < bd2) || (dpair.y < bd2))) {
                #pragma unroll
                for (int e = 0; e < 2; ++e) {
                    float d = dpair[e];
                    int   j = j0 + 2 * jj + e;
                    INS3(d, j, bd0, bd1, bd2, bi0, bi1, bi2);
                }
            }
        }
        const int o = (ch * TM + r) * 3;
        s_pd[o+0] = bd0; s_pd[o+1] = bd1; s_pd[o+2] = bd2;
        s_pi[o+0] = bi0; s_pi[o+1] = bi1; s_pi[o+2] = bi2;
    }
    __syncthreads();

    // ---------- merge B level 1: 256 threads, 4 chunks each ----------
    if (tid < 256) {
        const int row = tid & 63, grp = tid >> 6;
        float d0 = 3e38f, d1 = 3e38f, d2 = 3e38f;
        int   i0 = -1, i1 = -1, i2 = -1;
        #pragma unroll
        for (int c = 0; c < 4; ++c) {
            const int o = ((grp * 4 + c) * TM + row) * 3;
            #pragma unroll
            for (int k = 0; k < 3; ++k) {
                float d = s_pd[o + k]; int ix = s_pi[o + k];
                INS3(d, ix, d0, d1, d2, i0, i1, i2);
            }
        }
        float* sg = (float*)(s_buf + row * (APAD * 2) + grp * 32);
        sg[0] = d0; sg[1] = d1; sg[2] = d2;
        sg[3] = __int_as_float(i0); sg[4] = __int_as_float(i1); sg[5] = __int_as_float(i2);
    }
    __syncthreads();

    // ---------- merge B level 2: init from A-top3, insert partials; weights ----------
    if (tid < TM) {
        float d0 = s_m[tid][0], d1 = s_m[tid][1], d2 = s_m[tid][2];
        int   i0 = __float_as_int(s_m[tid][4]);
        int   i1 = __float_as_int(s_m[tid][5]);
        int   i2 = __float_as_int(s_m[tid][6]);
        #pragma unroll
        for (int g = 0; g < 4; ++g) {
            const float* sg = (const float*)(s_buf + tid * (APAD * 2) + g * 32);
            #pragma unroll
            for (int k = 0; k < 3; ++k) {
                // fake (bound,-1) entries have d >= current d2 -> rejected by strict <
                float d = sg[k]; int ix = __float_as_int(sg[3 + k]);
                INS3(d, ix, d0, d1, d2, i0, i1, i2);
            }
        }
        d0 = fmaxf(d0, 1e-10f); d1 = fmaxf(d1, 1e-10f); d2 = fmaxf(d2, 1e-10f);
        float v0 = 1.0f / d0, v1 = 1.0f / d1, v2 = 1.0f / d2;
        float s  = 1.0f / (v0 + v1 + v2);
        s_wt[tid][0] = v0 * s; s_wt[tid][1] = v1 * s; s_wt[tid][2] = v2 * s;
        s_idx[tid][0] = i0; s_idx[tid][1] = i1; s_idx[tid][2] = i2;
    }
    __syncthreads();

    // ---------- interp -> A cols 0..255 (wave-uniform row; 2-deep load pipe) ----------
    {
        const float* pb = p2 + (size_t)b * N2 * C2;
        const int col4 = (tid & 63) * 4;
        const int wvr  = tid >> 6;                       // 0..15
        float4 a0[2], a1[2], a2[2];
        {
            int rr = wvr;
            a0[0] = *(const float4*)(pb + (size_t)s_idx[rr][0] * C2 + col4);
            a1[0] = *(const float4*)(pb + (size_t)s_idx[rr][1] * C2 + col4);
            a2[0] = *(const float4*)(pb + (size_t)s_idx[rr][2] * C2 + col4);
        }
        #pragma unroll
        for (int m = 0; m < 4; ++m) {
            int cur = m & 1, nxt = cur ^ 1;
            if (m < 3) {
                int rn = wvr + (m + 1) * 16;
                a0[nxt] = *(const float4*)(pb + (size_t)s_idx[rn][0] * C2 + col4);
                a1[nxt] = *(const float4*)(pb + (size_t)s_idx[rn][1] * C2 + col4);
                a2[nxt] = *(const float4*)(pb + (size_t)s_idx[rn][2] * C2 + col4);
            }
            int rr = wvr + m * 16;
            float w0 = s_wt[rr][0], w1v = s_wt[rr][1], w2v = s_wt[rr][2];
            float e0 = w0 * a0[cur].x + w1v * a1[cur].x + w2v * a2[cur].x;
            float e1 = w0 * a0[cur].y + w1v * a1[cur].y + w2v * a2[cur].y;
            float e2 = w0 * a0[cur].z + w1v * a1[cur].z + w2v * a2[cur].z;
            float e3 = w0 * a0[cur].w + w1v * a1[cur].w + w2v * a2[cur].w;
            u32* w = (u32*)(A + rr * APAD + col4);
            w[0] = pack2(e0, e1);
            w[1] = pack2(e2, e3);
        }
    }
    __syncthreads();

    // ---------- empirical C/D map probe (2 MFMAs) ----------
    const int lane = tid & 63;
    const int wv   = tid >> 6;          // 0..15, wave -> 16-col slice
    const int lr   = lane & 15;
    const int lg   = lane >> 4;         // 0..3
    const int kb8  = lg * 8;
    const int wvb  = wv * 16;

    int id1[4], id2[4];
    {
        u16 rbf = f2b((float)lr);
        u16 c32 = f2b(1.0f / 32.0f);
        ABFrag pa, pc;
        u32 ra = (u32)rbf | ((u32)rbf << 16);
        u32 rc = (u32)c32 | ((u32)c32 << 16);
        pa.u[0] = pa.u[1] = pa.u[2] = pa.u[3] = ra;
        pc.u[0] = pc.u[1] = pc.u[2] = pc.u[3] = rc;
        floatx4 z = {0.f, 0.f, 0.f, 0.f};
        floatx4 D1 = __builtin_amdgcn_mfma_f32_16x16x32_bf16(pa.v, pc.v, z, 0, 0, 0); // row
        floatx4 D2 = __builtin_amdgcn_mfma_f32_16x16x32_bf16(pc.v, pa.v, z, 0, 0, 0); // col
        #pragma unroll
        for (int g = 0; g < 4; ++g) { id1[g] = (int)(D1[g] + 0.5f); id2[g] = (int)(D2[g] + 0.5f); }
    }

    // ---------- GEMM1 (K=384), 1-deep w-frag prefetch ----------
    floatx4 acc[4];
    #pragma unroll
    for (int i = 0; i < 4; ++i) acc[i] = floatx4{0.f, 0.f, 0.f, 0.f};
    {
        const u32x4* wf = w1F + (size_t)(wv * NKT1) * 64 + lane;
        ABFrag bfc; bfc.q = wf[0];
        #pragma unroll 2
        for (int kk = 0; kk < NKT1; ++kk) {
            ABFrag bfn;
            bfn.q = wf[(size_t)((kk + 1 < NKT1) ? kk + 1 : kk) * 64];
            ABFrag a[4];
            #pragma unroll
            for (int rt = 0; rt < 4; ++rt)
                a[rt].q = *(const u32x4*)(A + (rt * 16 + lr) * APAD + kk * 32 + kb8);
            #pragma unroll
            for (int rt = 0; rt < 4; ++rt)
                acc[rt] = __builtin_amdgcn_mfma_f32_16x16x32_bf16(a[rt].v, bfc.v, acc[rt], 0, 0, 0);
            bfc = bfn;
        }
    }
    __syncthreads();   // all waves done reading A

    // ---------- H = relu -> bf16 LDS [TM][HPAD] ----------
    u16* H = (u16*)s_buf;
    #pragma unroll
    for (int rt = 0; rt < 4; ++rt)
        #pragma unroll
        for (int g = 0; g < 4; ++g) {
            int row = rt * 16 + id1[g];
            int col = wvb + id2[g];
            H[row * HPAD + col] = f2b(fmaxf(acc[rt][g], 0.0f));
        }
    __syncthreads();

    // ---------- GEMM2 (K=256), 1-deep w-frag prefetch ----------
    floatx4 acc2[4];
    #pragma unroll
    for (int i = 0; i < 4; ++i) acc2[i] = floatx4{0.f, 0.f, 0.f, 0.f};
    {
        const u32x4* wf = w2F + (size_t)(wv * NKT2) * 64 + lane;
        ABFrag bfc; bfc.q = wf[0];
        #pragma unroll 2
        for (int kk = 0; kk < NKT2; ++kk) {
            ABFrag bfn;
            bfn.q = wf[(size_t)((kk + 1 < NKT2) ? kk + 1 : kk) * 64];
            ABFrag a[4];
            #pragma unroll
            for (int rt = 0; rt < 4; ++rt)
                a[rt].q = *(const u32x4*)(H + (rt * 16 + lr) * HPAD + kk * 32 + kb8);
            #pragma unroll
            for (int rt = 0; rt < 4; ++rt)
                acc2[rt] = __builtin_amdgcn_mfma_f32_16x16x32_bf16(a[rt].v, bfc.v, acc2[rt], 0, 0, 0);
            bfc = bfn;
        }
    }

    // ---------- relu -> f32 -> global ----------
    float* ob = out + ((size_t)b * N1 + t0) * FF;
    #pragma unroll
    for (int rt = 0; rt < 4; ++rt)
        #pragma unroll
        for (int g = 0; g < 4; ++g) {
            int row = rt * 16 + id1[g];
            int col = wvb + id2[g];
            ob[(size_t)row * FF + col] = fmaxf(acc2[rt][g], 0.0f);
        }
}

extern "C" void kernel_launch(void* const* d_in, const int* in_sizes, int n_in,
                              void* d_out, int out_size, void* d_ws, size_t ws_size,
                              hipStream_t stream)
{
    (void)in_sizes; (void)n_in; (void)out_size; (void)ws_size;
    const float* xyz1 = (const float*)d_in[0];
    const float* xyz2 = (const float*)d_in[1];
    const float* p1   = (const float*)d_in[2];
    const float* p2   = (const float*)d_in[3];
    const float* w1   = (const float*)d_in[4];
    const float* w2   = (const float*)d_in[5];
    float* out = (float*)d_out;

    u32x4* w1F = (u32x4*)d_ws;                      // 196608 B
    u32x4* w2F = w1F + 16 * NKT1 * 64;              // 131072 B
    float* xqw = (float*)(w2F + 16 * NKT2 * 64);    // 131072 B

    int prep_items = 16 * NKT1 * 64 + 16 * NKT2 * 64 + NB * N2;
    prep_kernel<<<(prep_items + 255) / 256, 256, 0, stream>>>(w1, w2, xyz2, w1F, w2F, xqw);
    fp_fused_kernel<<<NB * TILES_PER_B, NTHR, 0, stream>>>(
        xyz1, p1, p2, w1F, w2F, (const float4*)xqw, out);
}